// Round 6
// baseline (406.183 us; speedup 1.0000x reference)
//
#include <hip/hip_runtime.h>
#include <cstdint>
#include <cstddef>

typedef unsigned short u16;
typedef unsigned int   u32;
typedef unsigned short u16x4 __attribute__((ext_vector_type(4)));
typedef unsigned short u16x8 __attribute__((ext_vector_type(8)));
typedef unsigned int   u32x2 __attribute__((ext_vector_type(2)));
typedef unsigned int   u32x4 __attribute__((ext_vector_type(4)));
typedef __bf16 bf16x8 __attribute__((ext_vector_type(8)));
typedef float f32x4 __attribute__((ext_vector_type(4)));

#define MFMA16(a, b, c) __builtin_amdgcn_mfma_f32_16x16x32_bf16((a), (b), (c), 0, 0, 0)

__device__ __forceinline__ float bf2f(u16 h) {
  union { unsigned u; float f; } v; v.u = ((unsigned)h) << 16; return v.f;
}
__device__ __forceinline__ u16 f2bf(float f) {
  union { float f; unsigned u; } v; v.f = f;
  unsigned r = v.u + 0x7fffu + ((v.u >> 16) & 1u);
  return (u16)(r >> 16);
}
// pack two f32 -> (bf16(b)<<16)|bf16(a), RNE
__device__ __forceinline__ u32 pack2(float a, float b) {
  union { float f; u32 u; } ua, ub; ua.f = a; ub.f = b;
  u32 ra = ua.u + 0x7fffu + ((ua.u >> 16) & 1u);
  u32 rb = ub.u + 0x7fffu + ((ub.u >> 16) & 1u);
  return __builtin_amdgcn_perm(rb, ra, 0x07060302);
}
__device__ __forceinline__ void gll16(const u16* g, u16* l) {
  __builtin_amdgcn_global_load_lds(
      (const __attribute__((address_space(1))) void*)g,
      (__attribute__((address_space(3))) void*)l, 16, 0, 0);
}
__device__ __forceinline__ float fast_exp2(float x) {
#if __has_builtin(__builtin_amdgcn_exp2f)
  return __builtin_amdgcn_exp2f(x);
#else
  return exp2f(x);
#endif
}
// stage 8 f32 -> 8 bf16 into LDS (16B write)
__device__ __forceinline__ void stage8(const float* g, u16* l) {
  float4 u = *(const float4*)g;
  float4 w = *(const float4*)(g + 4);
  u32x4 q;
  q[0] = pack2(u.x, u.y); q[1] = pack2(u.z, u.w);
  q[2] = pack2(w.x, w.y); q[3] = pack2(w.z, w.w);
  *(u32x4*)l = q;
}

// ---------------------------------------------------------------------------
// QKV weight repack: f32 [H,1024,64] stacks -> bf16 Bt layout [3072][1024]
// ---------------------------------------------------------------------------
__global__ __launch_bounds__(256) void transpose_qkv(
    const float* __restrict__ Wq, const float* __restrict__ Wk,
    const float* __restrict__ Wv, u16* __restrict__ outb) {
  __shared__ u16 tile[32][33];
  const int z = blockIdx.z;            // 0..47
  const int which = z >> 4, h = z & 15;
  const float* in = (which == 0 ? Wq : (which == 1 ? Wk : Wv)) + (size_t)h * 1024 * 64;
  u16* out = outb + ((size_t)which * 1024 + h * 64) * 1024;   // [64][1024]
  const int tx = threadIdx.x & 31, ty = threadIdx.x >> 5;     // ty 0..7
  const int r0 = blockIdx.y * 32, c0 = blockIdx.x * 32;
  #pragma unroll
  for (int i = 0; i < 32; i += 8)
    tile[ty + i][tx] = f2bf(in[(size_t)(r0 + ty + i) * 64 + c0 + tx]);
  __syncthreads();
  #pragma unroll
  for (int i = 0; i < 32; i += 8)
    out[(size_t)(c0 + ty + i) * 1024 + r0 + tx] = tile[tx][ty + i];
}

// fused Wo/W1/W2 transpose: 1024 + 4096 + 4096 = 9216 tile-blocks
__global__ __launch_bounds__(256) void transpose_w(
    const float* __restrict__ Wo, const float* __restrict__ W1,
    const float* __restrict__ W2, u16* __restrict__ Wo_t,
    u16* __restrict__ W1_t, u16* __restrict__ W2_t) {
  __shared__ u16 tile[32][33];
  const int id = blockIdx.x;
  const float* in; u16* outp; int R, C, cx, ry;
  if (id < 1024)      { in = Wo; outp = Wo_t; R = 1024; C = 1024; cx = id & 31;  ry = id >> 5; }
  else if (id < 5120) { int t = id - 1024; in = W1; outp = W1_t; R = 1024; C = 4096; cx = t & 127; ry = t >> 7; }
  else                { int t = id - 5120; in = W2; outp = W2_t; R = 4096; C = 1024; cx = t & 31;  ry = t >> 5; }
  const int tx = threadIdx.x & 31, ty = threadIdx.x >> 5;
  const int r0 = ry * 32, c0 = cx * 32;
  #pragma unroll
  for (int i = 0; i < 32; i += 8)
    tile[ty + i][tx] = f2bf(in[(size_t)(r0 + ty + i) * C + c0 + tx]);
  __syncthreads();
  #pragma unroll
  for (int i = 0; i < 32; i += 8)
    outp[(size_t)(c0 + ty + i) * R + r0 + tx] = tile[tx][ty + i];
}

// fused prep: biasq (3072) + madd2 (4096, log2-domain mask addend)
__global__ __launch_bounds__(256) void prep_small(
    const float* __restrict__ bq, const float* __restrict__ bk,
    const float* __restrict__ bv, const int* __restrict__ mask,
    float* __restrict__ biasq, float* __restrict__ madd2) {
  int i = blockIdx.x * 256 + threadIdx.x;
  if (i < 3072) {
    biasq[i] = (i < 1024) ? bq[i] : (i < 2048 ? bk[i - 1024] : bv[i - 2048]);
  } else if (i < 7168) {
    int j = i - 3072;
    madd2[j] = mask[j] ? -23.083120f : -1.442695e9f;  // (-16 | -1e9) * log2(e)
  }
}

// ---------------------------------------------------------------------------
// GEMM 128x128, BK=64. C[M,N] = A[M,K](bf16 or f32) @ Bt[N,K](bf16)^T + bias.
// MODE 0: plain, 1: relu. AF32: A is f32, converted during LDS staging.
// ---------------------------------------------------------------------------
template <int MODE, int AF32>
__global__ __launch_bounds__(256) void gemm_bt(
    const u16* __restrict__ A, const float* __restrict__ Af,
    const u16* __restrict__ Bt, const float* __restrict__ bias,
    u16* __restrict__ C, int M, int N, int K) {
  __shared__ __align__(16) u16 As[2][128 * 32];
  __shared__ __align__(16) u16 Bs[2][128 * 32];
  const int tid = threadIdx.x;
  const int lane = tid & 63;
  const int wave = tid >> 6;
  const int m0 = blockIdx.y * 128;
  const int n0 = blockIdx.x * 128;
  const int wr = (wave >> 1) * 64;
  const int wc = (wave & 1) * 64;
  const int lrow = lane & 15;
  const int quad = lane >> 4;

  const int srow = lane >> 2;          // 0..15
  const int scol = (lane & 3) * 8;     // element col
  const u16 *gA1 = nullptr, *gA2 = nullptr;
  const float *fA1 = nullptr, *fA2 = nullptr;
  if (AF32) {
    fA1 = &Af[(size_t)(m0 + wave * 16 + srow) * K + scol];
    fA2 = &Af[(size_t)(m0 + 64 + wave * 16 + srow) * K + scol];
  } else {
    gA1 = &A[(size_t)(m0 + wave * 16 + srow) * K + scol];
    gA2 = &A[(size_t)(m0 + 64 + wave * 16 + srow) * K + scol];
  }
  const u16* gB1 = &Bt[(size_t)(n0 + wave * 16 + srow) * K + scol];
  const u16* gB2 = &Bt[(size_t)(n0 + 64 + wave * 16 + srow) * K + scol];
  const int soA1 = (wave * 16 + srow) * 32 + scol;
  const int soA2 = (wave * 16 + 64 + srow) * 32 + scol;
  const int so1 = (wave * 16) * 32;
  const int so2 = (wave * 16 + 64) * 32;

  f32x4 acc[4][4];
  #pragma unroll
  for (int i = 0; i < 4; ++i)
    #pragma unroll
    for (int j = 0; j < 4; ++j)
      acc[i][j] = (f32x4){0.f, 0.f, 0.f, 0.f};

  for (int k0 = 0; k0 < K; k0 += 64) {
    if (AF32) {
      stage8(fA1 + k0,      &As[0][soA1]);
      stage8(fA2 + k0,      &As[0][soA2]);
      stage8(fA1 + k0 + 32, &As[1][soA1]);
      stage8(fA2 + k0 + 32, &As[1][soA2]);
    } else {
      gll16(gA1 + k0, &As[0][so1]);
      gll16(gA2 + k0, &As[0][so2]);
      gll16(gA1 + k0 + 32, &As[1][so1]);
      gll16(gA2 + k0 + 32, &As[1][so2]);
    }
    gll16(gB1 + k0, &Bs[0][so1]);
    gll16(gB2 + k0, &Bs[0][so2]);
    gll16(gB1 + k0 + 32, &Bs[1][so1]);
    gll16(gB2 + k0 + 32, &Bs[1][so2]);
    __syncthreads();
    #pragma unroll
    for (int kb = 0; kb < 2; ++kb) {
      bf16x8 af[4], bfr[4];
      #pragma unroll
      for (int i = 0; i < 4; ++i) {
        af[i]  = *(const bf16x8*)&As[kb][(wr + i * 16 + lrow) * 32 + quad * 8];
        bfr[i] = *(const bf16x8*)&Bs[kb][(wc + i * 16 + lrow) * 32 + quad * 8];
      }
      #pragma unroll
      for (int fr = 0; fr < 4; ++fr)
        #pragma unroll
        for (int fc = 0; fc < 4; ++fc)
          acc[fr][fc] = MFMA16(af[fr], bfr[fc], acc[fr][fc]);
    }
    __syncthreads();
  }

  #pragma unroll
  for (int fr = 0; fr < 4; ++fr) {
    int rowb = m0 + wr + fr * 16 + quad * 4;
    #pragma unroll
    for (int fc = 0; fc < 4; ++fc) {
      int col = n0 + wc + fc * 16 + lrow;
      float bv = bias[col];
      #pragma unroll
      for (int r = 0; r < 4; ++r) {
        float v = acc[fr][fc][r] + bv;
        if (MODE == 1) v = fmaxf(v, 0.f);
        C[(size_t)(rowb + r) * N + col] = f2bf(v);
      }
    }
  }
}

// ---------------------------------------------------------------------------
// GEMM 64x128 tile, BK=64 (for N=1024 shapes: 512 blocks = 2/CU).
// ---------------------------------------------------------------------------
__global__ __launch_bounds__(256) void gemm64_bt(
    const u16* __restrict__ A, const u16* __restrict__ Bt,
    const float* __restrict__ bias, u16* __restrict__ C,
    int M, int N, int K) {
  __shared__ __align__(16) u16 As[2][64 * 32];
  __shared__ __align__(16) u16 Bs[2][128 * 32];
  const int tid = threadIdx.x;
  const int lane = tid & 63;
  const int wave = tid >> 6;
  const int m0 = blockIdx.y * 64;
  const int n0 = blockIdx.x * 128;
  const int wr = (wave >> 1) * 32;
  const int wc = (wave & 1) * 64;
  const int lrow = lane & 15;
  const int quad = lane >> 4;

  const int srow = lane >> 2;
  const int scol = (lane & 3) * 8;
  const u16* gA1 = &A[(size_t)(m0 + wave * 16 + srow) * K + scol];
  const u16* gB1 = &Bt[(size_t)(n0 + wave * 16 + srow) * K + scol];
  const u16* gB2 = &Bt[(size_t)(n0 + 64 + wave * 16 + srow) * K + scol];
  const int so1 = (wave * 16) * 32;
  const int so2 = (wave * 16 + 64) * 32;

  f32x4 acc[2][4];
  #pragma unroll
  for (int i = 0; i < 2; ++i)
    #pragma unroll
    for (int j = 0; j < 4; ++j)
      acc[i][j] = (f32x4){0.f, 0.f, 0.f, 0.f};

  for (int k0 = 0; k0 < K; k0 += 64) {
    gll16(gA1 + k0, &As[0][so1]);
    gll16(gB1 + k0, &Bs[0][so1]);
    gll16(gB2 + k0, &Bs[0][so2]);
    gll16(gA1 + k0 + 32, &As[1][so1]);
    gll16(gB1 + k0 + 32, &Bs[1][so1]);
    gll16(gB2 + k0 + 32, &Bs[1][so2]);
    __syncthreads();
    #pragma unroll
    for (int kb = 0; kb < 2; ++kb) {
      bf16x8 af[2], bfr[4];
      #pragma unroll
      for (int i = 0; i < 2; ++i)
        af[i] = *(const bf16x8*)&As[kb][(wr + i * 16 + lrow) * 32 + quad * 8];
      #pragma unroll
      for (int j = 0; j < 4; ++j)
        bfr[j] = *(const bf16x8*)&Bs[kb][(wc + j * 16 + lrow) * 32 + quad * 8];
      #pragma unroll
      for (int fr = 0; fr < 2; ++fr)
        #pragma unroll
        for (int fc = 0; fc < 4; ++fc)
          acc[fr][fc] = MFMA16(af[fr], bfr[fc], acc[fr][fc]);
    }
    __syncthreads();
  }

  #pragma unroll
  for (int fr = 0; fr < 2; ++fr) {
    int rowb = m0 + wr + fr * 16 + quad * 4;
    #pragma unroll
    for (int fc = 0; fc < 4; ++fc) {
      int col = n0 + wc + fc * 16 + lrow;
      float bv = bias[col];
      #pragma unroll
      for (int r = 0; r < 4; ++r) {
        float v = acc[fr][fc][r] + bv;
        C[(size_t)(rowb + r) * N + col] = f2bf(v);
      }
    }
  }
}

// ---------------------------------------------------------------------------
// Flash attention, transposed scores + static max, 2 q-tiles/wave, 64-key steps.
// exp in log2 domain: p = exp2(z * 0.125*log2e + madd2[key]).
// ---------------------------------------------------------------------------
__global__ __launch_bounds__(256) void attn_kernel(
    const u16* __restrict__ xqkv, const float* __restrict__ madd2,
    u16* __restrict__ ctx) {
  __shared__ __align__(16) u16 Ks[64][72];
  __shared__ __align__(16) u16 Vt[64][136];
  __shared__ __align__(16) u16 Ps[4][2][16][72];
  const int tid = threadIdx.x;
  const int lane = tid & 63;
  const int wave = tid >> 6;
  const int lrow = lane & 15;
  const int quad = lane >> 4;
  const int b = blockIdx.z, h = blockIdx.y;
  const int qb = blockIdx.x * 128 + wave * 16;
  const u16* Qp = xqkv + (size_t)b * 2048 * 3072 + h * 64;
  const u16* Kp = Qp + 1024;
  const u16* Vp = Qp + 2048;
  const float S2 = 0.18033688f;        // 0.125 * log2(e)

  bf16x8 qa[2][2];
  #pragma unroll
  for (int t = 0; t < 2; ++t) {
    qa[t][0] = *(const bf16x8*)&Qp[(size_t)(qb + t * 64 + lrow) * 3072 + quad * 8];
    qa[t][1] = *(const bf16x8*)&Qp[(size_t)(qb + t * 64 + lrow) * 3072 + 32 + quad * 8];
  }

  f32x4 o[2][4];
  #pragma unroll
  for (int t = 0; t < 2; ++t)
    #pragma unroll
    for (int i = 0; i < 4; ++i) o[t][i] = (f32x4){0.f, 0.f, 0.f, 0.f};
  float rsum[2] = {0.f, 0.f};

  const int ks_row = tid >> 3, ks_col = (tid & 7) * 8;
  const int v_dg = tid >> 4;           // 0..15
  const int v_kp = tid & 15;           // 0..15
  const float* maddb = madd2 + b * 2048;

  u16x8 kreg[2];
  u16x4 va[2], vb[2];
  #pragma unroll
  for (int sh = 0; sh < 2; ++sh) {
    kreg[sh] = *(const u16x8*)&Kp[(size_t)(sh * 32 + ks_row) * 3072 + ks_col];
    va[sh] = *(const u16x4*)&Vp[(size_t)(sh * 32 + 2 * v_kp) * 3072 + v_dg * 4];
    vb[sh] = *(const u16x4*)&Vp[(size_t)(sh * 32 + 2 * v_kp + 1) * 3072 + v_dg * 4];
  }

  for (int s0 = 0; s0 < 2048; s0 += 64) {
    __syncthreads();
    #pragma unroll
    for (int sh = 0; sh < 2; ++sh) {
      *(u16x8*)&Ks[sh * 32 + ks_row][ks_col] = kreg[sh];
      #pragma unroll
      for (int j = 0; j < 4; ++j) {
        u32 pk = ((u32)vb[sh][j] << 16) | (u32)va[sh][j];
        *(u32*)&Vt[v_dg * 4 + j][sh * 32 + 2 * v_kp] = pk;
      }
    }
    __syncthreads();
    if (s0 + 64 < 2048) {
      #pragma unroll
      for (int sh = 0; sh < 2; ++sh) {
        int sb = s0 + 64 + sh * 32;
        kreg[sh] = *(const u16x8*)&Kp[(size_t)(sb + ks_row) * 3072 + ks_col];
        va[sh] = *(const u16x4*)&Vp[(size_t)(sb + 2 * v_kp) * 3072 + v_dg * 4];
        vb[sh] = *(const u16x4*)&Vp[(size_t)(sb + 2 * v_kp + 1) * 3072 + v_dg * 4];
      }
    }

    bf16x8 kf[4][2], vf[4][2];
    #pragma unroll
    for (int kb = 0; kb < 4; ++kb) {
      kf[kb][0] = *(const bf16x8*)&Ks[kb * 16 + lrow][quad * 8];
      kf[kb][1] = *(const bf16x8*)&Ks[kb * 16 + lrow][32 + quad * 8];
    }
    #pragma unroll
    for (int nb = 0; nb < 4; ++nb) {
      vf[nb][0] = *(const bf16x8*)&Vt[nb * 16 + lrow][quad * 8];
      vf[nb][1] = *(const bf16x8*)&Vt[nb * 16 + lrow][32 + quad * 8];
    }

    #pragma unroll
    for (int t = 0; t < 2; ++t) {
      #pragma unroll
      for (int kb = 0; kb < 4; ++kb) {
        f32x4 z = (f32x4){0.f, 0.f, 0.f, 0.f};
        z = MFMA16(kf[kb][0], qa[t][0], z);
        z = MFMA16(kf[kb][1], qa[t][1], z);
        f32x4 m4 = *(const f32x4*)&maddb[s0 + kb * 16 + quad * 4];
        u32 pb[4];
        #pragma unroll
        for (int r = 0; r < 4; ++r) {
          float p = fast_exp2(fmaf(z[r], S2, m4[r]));
          rsum[t] += p;
          union { float f; u32 u; } cv; cv.f = p;
          pb[r] = cv.u + 0x8000u;
        }
        u32x2 w2;
        w2[0] = __builtin_amdgcn_perm(pb[1], pb[0], 0x07060302);
        w2[1] = __builtin_amdgcn_perm(pb[3], pb[2], 0x07060302);
        *(u32x2*)&Ps[wave][t][lrow][kb * 16 + quad * 4] = w2;
      }
      #pragma unroll
      for (int kh = 0; kh < 2; ++kh) {
        bf16x8 pa = *(const bf16x8*)&Ps[wave][t][lrow][kh * 32 + quad * 8];
        #pragma unroll
        for (int nb = 0; nb < 4; ++nb)
          o[t][nb] = MFMA16(pa, vf[nb][kh], o[t][nb]);
      }
    }
  }

  #pragma unroll
  for (int t = 0; t < 2; ++t) {
    float rs = rsum[t];
    rs += __shfl_xor(rs, 16, 64);
    rs += __shfl_xor(rs, 32, 64);
    float inv = 1.f / fmaxf(rs, 1e-30f);
    #pragma unroll
    for (int r = 0; r < 4; ++r) {
      float invq = __shfl(inv, quad * 4 + r, 64);
      int q = qb + t * 64 + quad * 4 + r;
      #pragma unroll
      for (int nb = 0; nb < 4; ++nb) {
        float v = o[t][nb][r] * invq;
        ctx[((size_t)b * 2048 + q) * 1024 + h * 64 + nb * 16 + lrow] = f2bf(v);
      }
    }
  }
}

// ---------------------------------------------------------------------------
// out = LayerNorm(x + y) * g + b,  D=1024, one block per token.
// ---------------------------------------------------------------------------
template <int IN_BF, int OUT_BF>
__global__ __launch_bounds__(256) void add_ln(
    const void* __restrict__ xa_, const u16* __restrict__ ya,
    const float* __restrict__ g, const float* __restrict__ bb,
    void* __restrict__ outp_) {
  __shared__ float red[8];
  const int tid = threadIdx.x;
  const size_t base = (size_t)blockIdx.x * 1024;
  const float* xf = (const float*)xa_;
  const u16*   xb = (const u16*)xa_;
  float v[4];
  float s = 0.f;
  #pragma unroll
  for (int i = 0; i < 4; ++i) {
    int c = i * 256 + tid;
    float xv = IN_BF ? bf2f(xb[base + c]) : xf[base + c];
    v[i] = xv + bf2f(ya[base + c]);
    s += v[i];
  }
  #pragma unroll
  for (int off = 32; off > 0; off >>= 1) s += __shfl_down(s, off, 64);
  if ((tid & 63) == 0) red[tid >> 6] = s;
  __syncthreads();
  float mean = (red[0] + red[1] + red[2] + red[3]) * (1.f / 1024.f);
  float s2 = 0.f;
  #pragma unroll
  for (int i = 0; i < 4; ++i) { float d = v[i] - mean; s2 += d * d; }
  #pragma unroll
  for (int off = 32; off > 0; off >>= 1) s2 += __shfl_down(s2, off, 64);
  if ((tid & 63) == 0) red[4 + (tid >> 6)] = s2;
  __syncthreads();
  float var = (red[4] + red[5] + red[6] + red[7]) * (1.f / 1024.f);
  float rstd = rsqrtf(var + 1e-5f);
  #pragma unroll
  for (int i = 0; i < 4; ++i) {
    int c = i * 256 + tid;
    float r = (v[i] - mean) * rstd * g[c] + bb[c];
    if (OUT_BF) ((u16*)outp_)[base + c] = f2bf(r);
    else        ((float*)outp_)[base + c] = r;
  }
}

// ---------------------------------------------------------------------------
extern "C" void kernel_launch(void* const* d_in, const int* in_sizes, int n_in,
                              void* d_out, int out_size, void* d_ws, size_t ws_size,
                              hipStream_t stream) {
  (void)in_sizes; (void)n_in; (void)out_size; (void)ws_size;
  const float* x    = (const float*)d_in[0];
  const int*   mask = (const int*)d_in[1];
  const float* Wq   = (const float*)d_in[2];
  const float* bq   = (const float*)d_in[3];
  const float* Wk   = (const float*)d_in[4];
  const float* bk   = (const float*)d_in[5];
  const float* Wv   = (const float*)d_in[6];
  const float* bv   = (const float*)d_in[7];
  const float* Wo   = (const float*)d_in[8];
  const float* bo   = (const float*)d_in[9];
  const float* ln1g = (const float*)d_in[10];
  const float* ln1b = (const float*)d_in[11];
  const float* ln2g = (const float*)d_in[12];
  const float* ln2b = (const float*)d_in[13];
  const float* W1   = (const float*)d_in[14];
  const float* b1   = (const float*)d_in[15];
  const float* W2   = (const float*)d_in[16];
  const float* b2   = (const float*)d_in[17];
  float* out = (float*)d_out;

  char* ws = (char*)d_ws;
  u16*   Wqkv_t = (u16*)(ws + 0);           // 6 MB
  u16*   Wo_t   = (u16*)(ws + 6291456);     // 2 MB
  u16*   W1_t   = (u16*)(ws + 8388608);     // 8 MB
  u16*   W2_t   = (u16*)(ws + 16777216);    // 8 MB
  u16*   xqkv   = (u16*)(ws + 25165824);    // [4096][3072] bf16, 24 MB
  u16*   ctx    = (u16*)(ws + 50331648);    // [4096][1024] bf16, 8 MB
  u16*   ff1    = (u16*)(ws + 25165824);    // 32 MB (overlays xqkv+ctx, dead by then)
  u16*   attout = (u16*)(ws + 58720256);    // 8 MB
  u16*   ff2    = attout;                   // overlays attout (dead after LN1)
  u16*   hbuf   = (u16*)(ws + 67108864);    // 8 MB
  float* biasq  = (float*)(ws + 75497472);  // 3072 f32
  float* madd2  = (float*)(ws + 75509760);  // 4096 f32  (total ~75.5 MB)

  // all prep upfront (3 launches, nothing on the critical path mid-pipeline)
  prep_small<<<28, 256, 0, stream>>>(bq, bk, bv, mask, biasq, madd2);
  transpose_qkv<<<dim3(2, 32, 48), 256, 0, stream>>>(Wq, Wk, Wv, Wqkv_t);
  transpose_w<<<9216, 256, 0, stream>>>(Wo, W1, W2, Wo_t, W1_t, W2_t);

  // QKV projection reads x (f32) directly, converting during A-staging
  gemm_bt<0, 1><<<dim3(24, 32), 256, 0, stream>>>(nullptr, x, Wqkv_t, biasq,
                                                  xqkv, 4096, 3072, 1024);
  attn_kernel<<<dim3(16, 16, 2), 256, 0, stream>>>(xqkv, madd2, ctx);
  gemm64_bt<<<dim3(8, 64), 256, 0, stream>>>(ctx, Wo_t, bo, attout, 4096, 1024, 1024);
  add_ln<0, 1><<<4096, 256, 0, stream>>>(x, attout, ln1g, ln1b, hbuf);
  gemm_bt<1, 0><<<dim3(32, 32), 256, 0, stream>>>(hbuf, nullptr, W1_t, b1,
                                                  ff1, 4096, 4096, 1024);
  gemm64_bt<<<dim3(8, 64), 256, 0, stream>>>(ff1, W2_t, b2, ff2, 4096, 1024, 4096);
  add_ln<1, 0><<<4096, 256, 0, stream>>>(hbuf, ff2, ln2g, ln2b, out);
}

// Round 7
// 379.707 us; speedup vs baseline: 1.0697x; 1.0697x over previous
//
#include <hip/hip_runtime.h>
#include <cstdint>
#include <cstddef>

typedef unsigned short u16;
typedef unsigned int   u32;
typedef unsigned short u16x4 __attribute__((ext_vector_type(4)));
typedef unsigned short u16x8 __attribute__((ext_vector_type(8)));
typedef unsigned int   u32x2 __attribute__((ext_vector_type(2)));
typedef __bf16 bf16x8 __attribute__((ext_vector_type(8)));
typedef float f32x4 __attribute__((ext_vector_type(4)));

#define MFMA16(a, b, c) __builtin_amdgcn_mfma_f32_16x16x32_bf16((a), (b), (c), 0, 0, 0)

__device__ __forceinline__ float bf2f(u16 h) {
  union { unsigned u; float f; } v; v.u = ((unsigned)h) << 16; return v.f;
}
__device__ __forceinline__ u16 f2bf(float f) {
  union { float f; unsigned u; } v; v.f = f;
  unsigned r = v.u + 0x7fffu + ((v.u >> 16) & 1u);
  return (u16)(r >> 16);
}
__device__ __forceinline__ void gll16(const u16* g, u16* l) {
  __builtin_amdgcn_global_load_lds(
      (const __attribute__((address_space(1))) void*)g,
      (__attribute__((address_space(3))) void*)l, 16, 0, 0);
}
__device__ __forceinline__ float fast_exp2(float x) {
#if __has_builtin(__builtin_amdgcn_exp2f)
  return __builtin_amdgcn_exp2f(x);
#else
  return exp2f(x);
#endif
}

// ---------------------------------------------------------------------------
// QKV weight repack: f32 [H,1024,64] stacks -> bf16 Bt layout [3072][1024]
// ---------------------------------------------------------------------------
__global__ __launch_bounds__(256) void transpose_qkv(
    const float* __restrict__ Wq, const float* __restrict__ Wk,
    const float* __restrict__ Wv, u16* __restrict__ outb) {
  __shared__ u16 tile[32][33];
  const int z = blockIdx.z;            // 0..47
  const int which = z >> 4, h = z & 15;
  const float* in = (which == 0 ? Wq : (which == 1 ? Wk : Wv)) + (size_t)h * 1024 * 64;
  u16* out = outb + ((size_t)which * 1024 + h * 64) * 1024;   // [64][1024]
  const int tx = threadIdx.x & 31, ty = threadIdx.x >> 5;     // ty 0..7
  const int r0 = blockIdx.y * 32, c0 = blockIdx.x * 32;
  #pragma unroll
  for (int i = 0; i < 32; i += 8)
    tile[ty + i][tx] = f2bf(in[(size_t)(r0 + ty + i) * 64 + c0 + tx]);
  __syncthreads();
  #pragma unroll
  for (int i = 0; i < 32; i += 8)
    out[(size_t)(c0 + ty + i) * 1024 + r0 + tx] = tile[tx][ty + i];
}

// fused Wo/W1/W2 transpose: 1024 + 4096 + 4096 = 9216 tile-blocks
__global__ __launch_bounds__(256) void transpose_w(
    const float* __restrict__ Wo, const float* __restrict__ W1,
    const float* __restrict__ W2, u16* __restrict__ Wo_t,
    u16* __restrict__ W1_t, u16* __restrict__ W2_t) {
  __shared__ u16 tile[32][33];
  const int id = blockIdx.x;
  const float* in; u16* outp; int R, C, cx, ry;
  if (id < 1024)      { in = Wo; outp = Wo_t; R = 1024; C = 1024; cx = id & 31;  ry = id >> 5; }
  else if (id < 5120) { int t = id - 1024; in = W1; outp = W1_t; R = 1024; C = 4096; cx = t & 127; ry = t >> 7; }
  else                { int t = id - 5120; in = W2; outp = W2_t; R = 4096; C = 1024; cx = t & 31;  ry = t >> 5; }
  const int tx = threadIdx.x & 31, ty = threadIdx.x >> 5;
  const int r0 = ry * 32, c0 = cx * 32;
  #pragma unroll
  for (int i = 0; i < 32; i += 8)
    tile[ty + i][tx] = f2bf(in[(size_t)(r0 + ty + i) * C + c0 + tx]);
  __syncthreads();
  #pragma unroll
  for (int i = 0; i < 32; i += 8)
    outp[(size_t)(c0 + ty + i) * R + r0 + tx] = tile[tx][ty + i];
}

// fused prep: biasq (3072) + madd2 (4096, log2-domain mask addend)
__global__ __launch_bounds__(256) void prep_small(
    const float* __restrict__ bq, const float* __restrict__ bk,
    const float* __restrict__ bv, const int* __restrict__ mask,
    float* __restrict__ biasq, float* __restrict__ madd2) {
  int i = blockIdx.x * 256 + threadIdx.x;
  if (i < 3072) {
    biasq[i] = (i < 1024) ? bq[i] : (i < 2048 ? bk[i - 1024] : bv[i - 2048]);
  } else if (i < 7168) {
    int j = i - 3072;
    madd2[j] = mask[j] ? -23.083120f : -1.442695e9f;  // (-16 | -1e9) * log2(e)
  }
}

// f32 -> bf16 bulk convert (n multiple of 4)
__global__ __launch_bounds__(256) void cvt_x(
    const float* __restrict__ in, u16* __restrict__ out, int n) {
  int i = (blockIdx.x * 256 + threadIdx.x) * 4;
  if (i >= n) return;
  const float4 v = *(const float4*)&in[i];
  u16x4 o;
  o[0] = f2bf(v.x); o[1] = f2bf(v.y); o[2] = f2bf(v.z); o[3] = f2bf(v.w);
  *(u16x4*)&out[i] = o;
}

// ---------------------------------------------------------------------------
// GEMM 128x128, BK=64, bf16 in/out. MODE 0: plain, 1: relu.
// ---------------------------------------------------------------------------
template <int MODE>
__global__ __launch_bounds__(256) void gemm_bt(
    const u16* __restrict__ A, const u16* __restrict__ Bt,
    const float* __restrict__ bias, u16* __restrict__ C,
    int M, int N, int K) {
  __shared__ __align__(16) u16 As[2][128 * 32];
  __shared__ __align__(16) u16 Bs[2][128 * 32];
  const int tid = threadIdx.x;
  const int lane = tid & 63;
  const int wave = tid >> 6;
  const int m0 = blockIdx.y * 128;
  const int n0 = blockIdx.x * 128;
  const int wr = (wave >> 1) * 64;
  const int wc = (wave & 1) * 64;
  const int lrow = lane & 15;
  const int quad = lane >> 4;

  const int srow = lane >> 2;          // 0..15
  const int scol = (lane & 3) * 8;     // u16 col
  const u16* gA1 = &A[(size_t)(m0 + wave * 16 + srow) * K + scol];
  const u16* gA2 = &A[(size_t)(m0 + 64 + wave * 16 + srow) * K + scol];
  const u16* gB1 = &Bt[(size_t)(n0 + wave * 16 + srow) * K + scol];
  const u16* gB2 = &Bt[(size_t)(n0 + 64 + wave * 16 + srow) * K + scol];
  const int so1 = (wave * 16) * 32;
  const int so2 = (wave * 16 + 64) * 32;

  f32x4 acc[4][4];
  #pragma unroll
  for (int i = 0; i < 4; ++i)
    #pragma unroll
    for (int j = 0; j < 4; ++j)
      acc[i][j] = (f32x4){0.f, 0.f, 0.f, 0.f};

  for (int k0 = 0; k0 < K; k0 += 64) {
    gll16(gA1 + k0, &As[0][so1]);
    gll16(gA2 + k0, &As[0][so2]);
    gll16(gB1 + k0, &Bs[0][so1]);
    gll16(gB2 + k0, &Bs[0][so2]);
    gll16(gA1 + k0 + 32, &As[1][so1]);
    gll16(gA2 + k0 + 32, &As[1][so2]);
    gll16(gB1 + k0 + 32, &Bs[1][so1]);
    gll16(gB2 + k0 + 32, &Bs[1][so2]);
    __syncthreads();
    #pragma unroll
    for (int kb = 0; kb < 2; ++kb) {
      bf16x8 af[4], bfr[4];
      #pragma unroll
      for (int i = 0; i < 4; ++i) {
        af[i]  = *(const bf16x8*)&As[kb][(wr + i * 16 + lrow) * 32 + quad * 8];
        bfr[i] = *(const bf16x8*)&Bs[kb][(wc + i * 16 + lrow) * 32 + quad * 8];
      }
      #pragma unroll
      for (int fr = 0; fr < 4; ++fr)
        #pragma unroll
        for (int fc = 0; fc < 4; ++fc)
          acc[fr][fc] = MFMA16(af[fr], bfr[fc], acc[fr][fc]);
    }
    __syncthreads();
  }

  #pragma unroll
  for (int fr = 0; fr < 4; ++fr) {
    int rowb = m0 + wr + fr * 16 + quad * 4;
    #pragma unroll
    for (int fc = 0; fc < 4; ++fc) {
      int col = n0 + wc + fc * 16 + lrow;
      float bv = bias[col];
      #pragma unroll
      for (int r = 0; r < 4; ++r) {
        float v = acc[fr][fc][r] + bv;
        if (MODE == 1) v = fmaxf(v, 0.f);
        C[(size_t)(rowb + r) * N + col] = f2bf(v);
      }
    }
  }
}

// ---------------------------------------------------------------------------
// Split-K GEMM 128x128, BK=64: grid (N/128, M/128, 2). Each z-half computes
// C_partial = A[:, kz*K/2:(kz+1)*K/2] @ Bt[:, same]^T, bf16, no bias.
// Partial kz goes to Cp + kz*M*N.
// ---------------------------------------------------------------------------
__global__ __launch_bounds__(256) void gemm_splitk(
    const u16* __restrict__ A, const u16* __restrict__ Bt,
    u16* __restrict__ Cp, int M, int N, int K) {
  __shared__ __align__(16) u16 As[2][128 * 32];
  __shared__ __align__(16) u16 Bs[2][128 * 32];
  const int tid = threadIdx.x;
  const int lane = tid & 63;
  const int wave = tid >> 6;
  const int m0 = blockIdx.y * 128;
  const int n0 = blockIdx.x * 128;
  const int kz = blockIdx.z;
  const int Kh = K >> 1;
  const int kbase = kz * Kh;
  const int wr = (wave >> 1) * 64;
  const int wc = (wave & 1) * 64;
  const int lrow = lane & 15;
  const int quad = lane >> 4;

  const int srow = lane >> 2;
  const int scol = (lane & 3) * 8;
  const u16* gA1 = &A[(size_t)(m0 + wave * 16 + srow) * K + kbase + scol];
  const u16* gA2 = &A[(size_t)(m0 + 64 + wave * 16 + srow) * K + kbase + scol];
  const u16* gB1 = &Bt[(size_t)(n0 + wave * 16 + srow) * K + kbase + scol];
  const u16* gB2 = &Bt[(size_t)(n0 + 64 + wave * 16 + srow) * K + kbase + scol];
  const int so1 = (wave * 16) * 32;
  const int so2 = (wave * 16 + 64) * 32;
  u16* C = Cp + (size_t)kz * M * N;

  f32x4 acc[4][4];
  #pragma unroll
  for (int i = 0; i < 4; ++i)
    #pragma unroll
    for (int j = 0; j < 4; ++j)
      acc[i][j] = (f32x4){0.f, 0.f, 0.f, 0.f};

  for (int k0 = 0; k0 < Kh; k0 += 64) {
    gll16(gA1 + k0, &As[0][so1]);
    gll16(gA2 + k0, &As[0][so2]);
    gll16(gB1 + k0, &Bs[0][so1]);
    gll16(gB2 + k0, &Bs[0][so2]);
    gll16(gA1 + k0 + 32, &As[1][so1]);
    gll16(gA2 + k0 + 32, &As[1][so2]);
    gll16(gB1 + k0 + 32, &Bs[1][so1]);
    gll16(gB2 + k0 + 32, &Bs[1][so2]);
    __syncthreads();
    #pragma unroll
    for (int kb = 0; kb < 2; ++kb) {
      bf16x8 af[4], bfr[4];
      #pragma unroll
      for (int i = 0; i < 4; ++i) {
        af[i]  = *(const bf16x8*)&As[kb][(wr + i * 16 + lrow) * 32 + quad * 8];
        bfr[i] = *(const bf16x8*)&Bs[kb][(wc + i * 16 + lrow) * 32 + quad * 8];
      }
      #pragma unroll
      for (int fr = 0; fr < 4; ++fr)
        #pragma unroll
        for (int fc = 0; fc < 4; ++fc)
          acc[fr][fc] = MFMA16(af[fr], bfr[fc], acc[fr][fc]);
    }
    __syncthreads();
  }

  #pragma unroll
  for (int fr = 0; fr < 4; ++fr) {
    int rowb = m0 + wr + fr * 16 + quad * 4;
    #pragma unroll
    for (int fc = 0; fc < 4; ++fc) {
      int col = n0 + wc + fc * 16 + lrow;
      #pragma unroll
      for (int r = 0; r < 4; ++r)
        C[(size_t)(rowb + r) * N + col] = f2bf(acc[fr][fc][r]);
    }
  }
}

// ---------------------------------------------------------------------------
// Flash attention, transposed scores + static max, 2 q-tiles/wave, 64-key steps.
// p = exp2(z * 0.125*log2e + madd2[key]).
// ---------------------------------------------------------------------------
__global__ __launch_bounds__(256) void attn_kernel(
    const u16* __restrict__ xqkv, const float* __restrict__ madd2,
    u16* __restrict__ ctx) {
  __shared__ __align__(16) u16 Ks[64][72];
  __shared__ __align__(16) u16 Vt[64][136];
  __shared__ __align__(16) u16 Ps[4][2][16][72];
  const int tid = threadIdx.x;
  const int lane = tid & 63;
  const int wave = tid >> 6;
  const int lrow = lane & 15;
  const int quad = lane >> 4;
  const int b = blockIdx.z, h = blockIdx.y;
  const int qb = blockIdx.x * 128 + wave * 16;
  const u16* Qp = xqkv + (size_t)b * 2048 * 3072 + h * 64;
  const u16* Kp = Qp + 1024;
  const u16* Vp = Qp + 2048;
  const float S2 = 0.18033688f;        // 0.125 * log2(e)

  bf16x8 qa[2][2];
  #pragma unroll
  for (int t = 0; t < 2; ++t) {
    qa[t][0] = *(const bf16x8*)&Qp[(size_t)(qb + t * 64 + lrow) * 3072 + quad * 8];
    qa[t][1] = *(const bf16x8*)&Qp[(size_t)(qb + t * 64 + lrow) * 3072 + 32 + quad * 8];
  }

  f32x4 o[2][4];
  #pragma unroll
  for (int t = 0; t < 2; ++t)
    #pragma unroll
    for (int i = 0; i < 4; ++i) o[t][i] = (f32x4){0.f, 0.f, 0.f, 0.f};
  float rsum[2] = {0.f, 0.f};

  const int ks_row = tid >> 3, ks_col = (tid & 7) * 8;
  const int v_dg = tid >> 4;
  const int v_kp = tid & 15;
  const float* maddb = madd2 + b * 2048;

  u16x8 kreg[2];
  u16x4 va[2], vb[2];
  #pragma unroll
  for (int sh = 0; sh < 2; ++sh) {
    kreg[sh] = *(const u16x8*)&Kp[(size_t)(sh * 32 + ks_row) * 3072 + ks_col];
    va[sh] = *(const u16x4*)&Vp[(size_t)(sh * 32 + 2 * v_kp) * 3072 + v_dg * 4];
    vb[sh] = *(const u16x4*)&Vp[(size_t)(sh * 32 + 2 * v_kp + 1) * 3072 + v_dg * 4];
  }

  for (int s0 = 0; s0 < 2048; s0 += 64) {
    __syncthreads();
    #pragma unroll
    for (int sh = 0; sh < 2; ++sh) {
      *(u16x8*)&Ks[sh * 32 + ks_row][ks_col] = kreg[sh];
      #pragma unroll
      for (int j = 0; j < 4; ++j) {
        u32 pk = ((u32)vb[sh][j] << 16) | (u32)va[sh][j];
        *(u32*)&Vt[v_dg * 4 + j][sh * 32 + 2 * v_kp] = pk;
      }
    }
    __syncthreads();
    if (s0 + 64 < 2048) {
      #pragma unroll
      for (int sh = 0; sh < 2; ++sh) {
        int sb = s0 + 64 + sh * 32;
        kreg[sh] = *(const u16x8*)&Kp[(size_t)(sb + ks_row) * 3072 + ks_col];
        va[sh] = *(const u16x4*)&Vp[(size_t)(sb + 2 * v_kp) * 3072 + v_dg * 4];
        vb[sh] = *(const u16x4*)&Vp[(size_t)(sb + 2 * v_kp + 1) * 3072 + v_dg * 4];
      }
    }

    bf16x8 kf[4][2], vf[4][2];
    #pragma unroll
    for (int kb = 0; kb < 4; ++kb) {
      kf[kb][0] = *(const bf16x8*)&Ks[kb * 16 + lrow][quad * 8];
      kf[kb][1] = *(const bf16x8*)&Ks[kb * 16 + lrow][32 + quad * 8];
    }
    #pragma unroll
    for (int nb = 0; nb < 4; ++nb) {
      vf[nb][0] = *(const bf16x8*)&Vt[nb * 16 + lrow][quad * 8];
      vf[nb][1] = *(const bf16x8*)&Vt[nb * 16 + lrow][32 + quad * 8];
    }

    #pragma unroll
    for (int t = 0; t < 2; ++t) {
      #pragma unroll
      for (int kb = 0; kb < 4; ++kb) {
        f32x4 z = (f32x4){0.f, 0.f, 0.f, 0.f};
        z = MFMA16(kf[kb][0], qa[t][0], z);
        z = MFMA16(kf[kb][1], qa[t][1], z);
        f32x4 m4 = *(const f32x4*)&maddb[s0 + kb * 16 + quad * 4];
        u32 pb[4];
        #pragma unroll
        for (int r = 0; r < 4; ++r) {
          float p = fast_exp2(fmaf(z[r], S2, m4[r]));
          rsum[t] += p;
          union { float f; u32 u; } cv; cv.f = p;
          pb[r] = cv.u + 0x8000u;
        }
        u32x2 w2;
        w2[0] = __builtin_amdgcn_perm(pb[1], pb[0], 0x07060302);
        w2[1] = __builtin_amdgcn_perm(pb[3], pb[2], 0x07060302);
        *(u32x2*)&Ps[wave][t][lrow][kb * 16 + quad * 4] = w2;
      }
      #pragma unroll
      for (int kh = 0; kh < 2; ++kh) {
        bf16x8 pa = *(const bf16x8*)&Ps[wave][t][lrow][kh * 32 + quad * 8];
        #pragma unroll
        for (int nb = 0; nb < 4; ++nb)
          o[t][nb] = MFMA16(pa, vf[nb][kh], o[t][nb]);
      }
    }
  }

  #pragma unroll
  for (int t = 0; t < 2; ++t) {
    float rs = rsum[t];
    rs += __shfl_xor(rs, 16, 64);
    rs += __shfl_xor(rs, 32, 64);
    float inv = 1.f / fmaxf(rs, 1e-30f);
    #pragma unroll
    for (int r = 0; r < 4; ++r) {
      float invq = __shfl(inv, quad * 4 + r, 64);
      int q = qb + t * 64 + quad * 4 + r;
      #pragma unroll
      for (int nb = 0; nb < 4; ++nb) {
        float v = o[t][nb][r] * invq;
        ctx[((size_t)b * 2048 + q) * 1024 + h * 64 + nb * 16 + lrow] = f2bf(v);
      }
    }
  }
}

// ---------------------------------------------------------------------------
// out = LayerNorm(x + p0 + p1 + cb) * g + b  (split-K combine fused in).
// IN_BF: residual dtype (1=bf16, 0=f32). OUT_BF: output dtype.
// ---------------------------------------------------------------------------
template <int IN_BF, int OUT_BF>
__global__ __launch_bounds__(256) void add_ln2p(
    const void* __restrict__ xa_, const u16* __restrict__ p0,
    const u16* __restrict__ p1, const float* __restrict__ cb,
    const float* __restrict__ g, const float* __restrict__ bb,
    void* __restrict__ outp_) {
  __shared__ float red[8];
  const int tid = threadIdx.x;
  const size_t base = (size_t)blockIdx.x * 1024;
  const float* xf = (const float*)xa_;
  const u16*   xb = (const u16*)xa_;
  float v[4];
  float s = 0.f;
  #pragma unroll
  for (int i = 0; i < 4; ++i) {
    int c = i * 256 + tid;
    float xv = IN_BF ? bf2f(xb[base + c]) : xf[base + c];
    v[i] = xv + bf2f(p0[base + c]) + bf2f(p1[base + c]) + cb[c];
    s += v[i];
  }
  #pragma unroll
  for (int off = 32; off > 0; off >>= 1) s += __shfl_down(s, off, 64);
  if ((tid & 63) == 0) red[tid >> 6] = s;
  __syncthreads();
  float mean = (red[0] + red[1] + red[2] + red[3]) * (1.f / 1024.f);
  float s2 = 0.f;
  #pragma unroll
  for (int i = 0; i < 4; ++i) { float d = v[i] - mean; s2 += d * d; }
  #pragma unroll
  for (int off = 32; off > 0; off >>= 1) s2 += __shfl_down(s2, off, 64);
  if ((tid & 63) == 0) red[4 + (tid >> 6)] = s2;
  __syncthreads();
  float var = (red[4] + red[5] + red[6] + red[7]) * (1.f / 1024.f);
  float rstd = rsqrtf(var + 1e-5f);
  #pragma unroll
  for (int i = 0; i < 4; ++i) {
    int c = i * 256 + tid;
    float r = (v[i] - mean) * rstd * g[c] + bb[c];
    if (OUT_BF) ((u16*)outp_)[base + c] = f2bf(r);
    else        ((float*)outp_)[base + c] = r;
  }
}

// ---------------------------------------------------------------------------
extern "C" void kernel_launch(void* const* d_in, const int* in_sizes, int n_in,
                              void* d_out, int out_size, void* d_ws, size_t ws_size,
                              hipStream_t stream) {
  (void)in_sizes; (void)n_in; (void)out_size; (void)ws_size;
  const float* x    = (const float*)d_in[0];
  const int*   mask = (const int*)d_in[1];
  const float* Wq   = (const float*)d_in[2];
  const float* bq   = (const float*)d_in[3];
  const float* Wk   = (const float*)d_in[4];
  const float* bk   = (const float*)d_in[5];
  const float* Wv   = (const float*)d_in[6];
  const float* bv   = (const float*)d_in[7];
  const float* Wo   = (const float*)d_in[8];
  const float* bo   = (const float*)d_in[9];
  const float* ln1g = (const float*)d_in[10];
  const float* ln1b = (const float*)d_in[11];
  const float* ln2g = (const float*)d_in[12];
  const float* ln2b = (const float*)d_in[13];
  const float* W1   = (const float*)d_in[14];
  const float* b1   = (const float*)d_in[15];
  const float* W2   = (const float*)d_in[16];
  const float* b2   = (const float*)d_in[17];
  float* out = (float*)d_out;

  char* ws = (char*)d_ws;
  u16*   Wqkv_t = (u16*)(ws + 0);           // 6 MB; later FF2 partial0 (8 MB)
  u16*   fp     = (u16*)(ws + 0);           // FF2 partials: [0,8M) + [8M,16M)
  u16*   Wo_t   = (u16*)(ws + 6291456);     // 2 MB
  u16*   W1_t   = (u16*)(ws + 8388608);     // 8 MB; later FF2 partial1
  u16*   W2_t   = (u16*)(ws + 16777216);    // 8 MB
  u16*   xqkv   = (u16*)(ws + 25165824);    // [4096][3072] bf16, 24 MB
  u16*   wp     = (u16*)(ws + 25165824);    // Wo partials 2x8 MB (xqkv dead after attn)
  u16*   xb     = (u16*)(ws + 50331648);    // 8 MB (dead after QKV gemm)
  u16*   ctx    = (u16*)(ws + 50331648);    // [4096][1024] bf16, 8 MB (after attn)
  u16*   ff1    = (u16*)(ws + 25165824);    // 32 MB (overlays xqkv+ctx; live LN1->FF2)
  u16*   hbuf   = (u16*)(ws + 67108864);    // 8 MB
  float* biasq  = (float*)(ws + 75497472);  // 3072 f32
  float* madd2  = (float*)(ws + 75509760);  // 4096 f32  (total ~75.5 MB)

  prep_small<<<28, 256, 0, stream>>>(bq, bk, bv, mask, biasq, madd2);
  transpose_qkv<<<dim3(2, 32, 48), 256, 0, stream>>>(Wq, Wk, Wv, Wqkv_t);
  transpose_w<<<9216, 256, 0, stream>>>(Wo, W1, W2, Wo_t, W1_t, W2_t);
  cvt_x<<<4096, 256, 0, stream>>>(x, xb, 4194304);

  gemm_bt<0><<<dim3(24, 32), 256, 0, stream>>>(xb, Wqkv_t, biasq, xqkv,
                                               4096, 3072, 1024);
  attn_kernel<<<dim3(16, 16, 2), 256, 0, stream>>>(xqkv, madd2, ctx);
  // Wo projection, split-K=2 -> bf16 partials in dead xqkv space
  gemm_splitk<<<dim3(8, 32, 2), 256, 0, stream>>>(ctx, Wo_t, wp, 4096, 1024, 1024);
  add_ln2p<0, 1><<<4096, 256, 0, stream>>>(x, wp, wp + 4194304, bo,
                                           ln1g, ln1b, hbuf);
  gemm_bt<1><<<dim3(32, 32), 256, 0, stream>>>(hbuf, W1_t, b1, ff1,
                                               4096, 4096, 1024);
  // FF2, split-K=2 -> partials in dead Wqkv_t/W1_t space
  gemm_splitk<<<dim3(8, 32, 2), 256, 0, stream>>>(ff1, W2_t, fp, 4096, 1024, 4096);
  add_ln2p<1, 0><<<4096, 256, 0, stream>>>(hbuf, fp, fp + 4194304, b2,
                                           ln2g, ln2b, out);
}